// Round 10
// baseline (225.619 us; speedup 1.0000x reference)
//
#include <hip/hip_runtime.h>
#include <math.h>
#include <stdint.h>

// Problem constants (fixed by setup_inputs)
constexpr int K_ = 4, B_ = 8, T_ = 800, C_ = 80, S_ = 128, Z_ = 32;
constexpr int KB_ = K_ * B_;        // 32
constexpr int TC_ = T_ * C_;        // 64000

#define BIGV   1e8f
#define WARP_V 256.0f

// R22 layout: g=4 shear (Q[u] covers cells (i, j=u-(i>>2))) + chunk-major row
// permutation. Row stride 1024 floats; float index 256k + 4l + e holds
// original column i = 16l + 4k + e (l=lane 0..49, k=chunk 0..3, e=0..3).
// => dtw load instruction k reads rowbase + 1024k*4B + 16B*lane: CONTIGUOUS
// across lanes (4 lanes/cacheline) instead of stride-64B (1 line/lane).
// R21's 256 line-requests/step (the measured ~265 cy/step floor) -> ~52.
constexpr int NU_   = 999;            // u = j + (i>>2) <= 799 + 199 = 998
constexpr int ROWF_ = 1024;           // floats per u-row (800 real, permuted)
constexpr int SLAB_ = NU_ * ROWF_;    // 1,022,976 floats/problem (131 MB total)

__device__ __forceinline__ float sigmoidf_(float v) {
    return 1.f / (1.f + __expf(-v));
}

__device__ __forceinline__ int permidx_(int i) {   // original column -> row float idx
    return 256 * ((i >> 2) & 3) + 4 * (i >> 4) + (i & 3);
}

// ---------------------------------------------------------------- ghost cells j<0 -> BIG
// Chain c (c>0) of each lane reads j = -1..-c before its first real column:
// ghosts at Q[(i>>2)-k][i], k=1..((i>>2)&3). 24 per 16-row block, 1200/problem.
__global__ void fill_edge(float* __restrict__ Dm) {
    int kb = blockIdx.x;
    #pragma unroll
    for (int m = 0; m < 5; ++m) {
        int idx = threadIdx.x + 256 * m;
        if (idx >= 1200) break;
        int blk = idx / 24, rem = idx % 24;
        int row, k;
        if (rem < 4)       { row = 4 + rem;                 k = 1; }
        else if (rem < 12) { int e = rem - 4;  row = 8 + (e >> 1);  k = 1 + (e & 1); }
        else               { int e = rem - 12; row = 12 + e / 3;    k = 1 + e % 3; }
        int i = 16 * blk + row;
        int u = 4 * blk + (row >> 2) - k;
        Dm[(size_t)kb * SLAB_ + (size_t)u * ROWF_ + permidx_(i)] = BIGV;
    }
}

// ---------------------------------------------------------------- banded GEMM -> sheared Q (norms fused)
// R20 single-stage structure; R22 epilogue: g=4 shear + chunk-major permute.
__global__ __launch_bounds__(256) void gemm_band(const float* __restrict__ mel_iters,
                                                 const float* __restrict__ mel_targets,
                                                 float* __restrict__ Dm) {
    const int kb = blockIdx.z;
    const int b  = kb & 7;
    const int ti = blockIdx.y;
    const int tj = ti + (int)blockIdx.x - 2;
    if ((unsigned)tj > 12u) return;

    const float* __restrict__ Xb = mel_iters + (size_t)kb * TC_;
    const float* __restrict__ Yb = mel_targets + (size_t)b * TC_;

    __shared__ float smem[10880];            // xa[80][68] | ya[80][68]; phase2: Zt[79][65]
    __shared__ float x2s[64], y2s[64];
    float (*xa)[68] = (float(*)[68])smem;
    float (*ya)[68] = (float(*)[68])(smem + 5440);

    const int tid = threadIdx.x;
    const int tx = tid & 15, ty = tid >> 4;
    const int i0 = ti * 64, j0 = tj * 64;

    // ---- single-stage: sigmoid(X) 64x80 and sigmoid(Y) 64x80 into LDS
    {
        const int row = tid & 63, seg = tid >> 6;      // 4 threads per row
        const int gi = min(i0 + row, T_ - 1);
        const int gj = min(j0 + row, T_ - 1);
        const float4* Xr = (const float4*)(Xb + (size_t)gi * C_);
        const float4* Yr = (const float4*)(Yb + (size_t)gj * C_);
        #pragma unroll
        for (int m = 0; m < 5; ++m) {
            const int k4 = seg * 5 + m;
            float4 xv = Xr[k4], yv = Yr[k4];
            const int k = k4 * 4;
            xa[k + 0][row] = sigmoidf_(xv.x); xa[k + 1][row] = sigmoidf_(xv.y);
            xa[k + 2][row] = sigmoidf_(xv.z); xa[k + 3][row] = sigmoidf_(xv.w);
            ya[k + 0][row] = sigmoidf_(yv.x); ya[k + 1][row] = sigmoidf_(yv.y);
            ya[k + 2][row] = sigmoidf_(yv.z); ya[k + 3][row] = sigmoidf_(yv.w);
        }
    }
    __syncthreads();

    // ---- row norms, k ascending
    if (tid < 64) {
        float s = 0.f;
        for (int k = 0; k < C_; ++k) { float v = xa[k][tid]; s += v * v; }
        x2s[tid] = s;
    } else if (tid < 128) {
        float s = 0.f;
        for (int k = 0; k < C_; ++k) { float v = ya[k][tid - 64]; s += v * v; }
        y2s[tid - 64] = s;
    }

    // ---- 80-deep FMA
    float acc[4][4] = {};
    #pragma unroll 16
    for (int k = 0; k < C_; ++k) {
        float4 av = *(const float4*)&xa[k][ty * 4];
        float4 bv = *(const float4*)&ya[k][tx * 4];
        acc[0][0] += av.x * bv.x; acc[0][1] += av.x * bv.y; acc[0][2] += av.x * bv.z; acc[0][3] += av.x * bv.w;
        acc[1][0] += av.y * bv.x; acc[1][1] += av.y * bv.y; acc[1][2] += av.y * bv.z; acc[1][3] += av.y * bv.w;
        acc[2][0] += av.z * bv.x; acc[2][1] += av.z * bv.y; acc[2][2] += av.z * bv.z; acc[2][3] += av.z * bv.w;
        acc[3][0] += av.w * bv.x; acc[3][1] += av.w * bv.y; acc[3][2] += av.w * bv.z; acc[3][3] += av.w * bv.w;
    }
    __syncthreads();

    float xs2[4], ys2[4];
    #pragma unroll
    for (int r = 0; r < 4; ++r) xs2[r] = x2s[ty * 4 + r];
    #pragma unroll
    for (int c = 0; c < 4; ++c) ys2[c] = y2s[tx * 4 + c];

    // sheared LDS tile: Zt[u_rel][iLoc], u_rel = jrel + (iLoc>>2) = 4tx+c + ty
    float* Zt = smem;                     // [79][65]
    const int sb = ty;
    #pragma unroll
    for (int r = 0; r < 4; ++r)
        #pragma unroll
        for (int c = 0; c < 4; ++c)
            Zt[(4 * tx + c + sb) * 65 + (4 * ty + r)] = xs2[r] + ys2[c] - 2.f * acc[r][c];
    __syncthreads();

    // u-row stores with chunk-major permute: i = i0+lane ->
    // nidx = 256*((lane>>2)&3) + 16*ti + 4*(lane>>4) + (lane&3)  (4 lines/store)
    const int w0 = tid >> 6;              // wave id 0..3
    const int lane = tid & 63;
    const int iGlob = i0 + lane;
    const int sbl = lane >> 2;            // (i>>2) - 16ti, 0..15
    const bool iok = iGlob < T_;
    const int nidx = 256 * ((lane >> 2) & 3) + 16 * ti + 4 * (lane >> 4) + (lane & 3);
    const size_t ub = (size_t)(j0 + 16 * ti) * ROWF_ + nidx;
    #pragma unroll
    for (int it = 0; it < 20; ++it) {
        int w = w0 + it * 4;
        if (w > 78) break;
        int jrel = w - sbl;
        if (iok && (unsigned)jrel < 64u && (j0 + jrel) < T_)
            Dm[(size_t)kb * SLAB_ + ub + (size_t)w * ROWF_] = Zt[w * 65 + lane];
    }
}

// ---------------------------------------------------------------- single-wave hard-min DTW, g=4, inline asm
// R22 = R21 DP (verified, absmax 0) with coalesced addressing: instruction k
// loads rowbase + 4096*u + 1024k + 16*lane bytes (contiguous across lanes).
// Slot register contents identical: reg 4k+e = column 16lc+4k+e.
// Register map:
//   v42 = BIG  v43,v44 = temps  v45 = tinE  v46 = tinWE  v47 = tinO  v48 = tinWO
//   sE = v50-65  wE = v66-81  sO = v82-97  wO = v98-113
//   ring: 8 slots x 16 floats = v114-v241, 32 loads in flight, wait vmcnt(28)

#define QUAD(s0,w0,d0,u0,l0,q0, s1,w1,d1,u1,l1,q1, s2,w2,d2,u2,l2,q2, s3,w3,d3,u3,l3,q3) \
  "v_min3_f32 v" #s0 ", v" #d0 ", v" #u0 ", v" #l0 "\n\t" \
  "v_min3_f32 v" #s1 ", v" #d1 ", v" #u1 ", v" #l1 "\n\t" \
  "v_min3_f32 v" #s2 ", v" #d2 ", v" #u2 ", v" #l2 "\n\t" \
  "v_min3_f32 v" #s3 ", v" #d3 ", v" #u3 ", v" #l3 "\n\t" \
  "v_add_f32 v" #s0 ", v" #s0 ", v" #q0 "\n\t" \
  "v_add_f32 v" #s1 ", v" #s1 ", v" #q1 "\n\t" \
  "v_add_f32 v" #s2 ", v" #s2 ", v" #q2 "\n\t" \
  "v_add_f32 v" #s3 ", v" #s3 ", v" #q3 "\n\t" \
  "v_add_f32 v" #w0 ", %[wK], v" #s0 "\n\t" \
  "v_add_f32 v" #w1 ", %[wK], v" #s1 "\n\t" \
  "v_add_f32 v" #w2 ", %[wK], v" #s2 "\n\t" \
  "v_add_f32 v" #w3 ", %[wK], v" #s3 "\n\t"

// STEP_E: reads sE/wE (+tinE,tinWO), writes sO/wO. Quads over cells {q,q+4,q+8,q+12}.
#define STEP_E(q0,q1,q2,q3,q4,q5,q6,q7,q8,q9,q10,q11,q12,q13,q14,q15) \
  QUAD(82,98,45,48,66,q0,    86,102,85,69,70,q4,   90,106,89,73,74,q8,   94,110,93,77,78,q12) \
  QUAD(83,99,50,98,67,q1,    87,103,54,102,71,q5,  91,107,58,106,75,q9,  95,111,62,110,79,q13) \
  QUAD(84,100,51,99,68,q2,   88,104,55,103,72,q6,  92,108,59,107,76,q10, 96,112,63,111,80,q14) \
  QUAD(85,101,52,100,69,q3,  89,105,56,104,73,q7,  93,109,60,108,77,q11, 97,113,64,112,81,q15)

// STEP_O: reads sO/wO (+tinO,tinWE), writes sE/wE.
#define STEP_O(q0,q1,q2,q3,q4,q5,q6,q7,q8,q9,q10,q11,q12,q13,q14,q15) \
  QUAD(50,66,47,46,98,q0,    54,70,53,101,102,q4,  58,74,57,105,106,q8,  62,78,61,109,110,q12) \
  QUAD(51,67,82,66,99,q1,    55,71,86,70,103,q5,   59,75,90,74,107,q9,   63,79,94,78,111,q13) \
  QUAD(52,68,83,67,100,q2,   56,72,87,71,104,q6,   60,76,91,75,108,q10,  64,80,95,79,112,q14) \
  QUAD(53,69,84,68,101,q3,   57,73,88,72,105,q7,   61,77,92,76,109,q11,  65,81,96,80,113,q15)

#define HO_E \
  "s_nop 1\n\t" \
  "v_mov_b32_dpp v43, v97 wave_shr:1 row_mask:0xf bank_mask:0xf bound_ctrl:0\n\t" \
  "v_cndmask_b32 v45, v43, v42, %[msk]\n\t" \
  "v_add_f32 v46, %[wK], v45\n\t"

#define HO_O \
  "s_nop 1\n\t" \
  "v_mov_b32_dpp v43, v65 wave_shr:1 row_mask:0xf bank_mask:0xf bound_ctrl:0\n\t" \
  "v_cndmask_b32 v47, v43, v42, %[msk]\n\t" \
  "v_add_f32 v48, %[wK], v47\n\t"

#define PREF(r0,r1,r2,r3,K) \
  "s_add_u32 %[st], %[su], " #K "\n\t" \
  "v_med3_i32 v43, %[st], %[vlo], %[vhi]\n\t" \
  "v_mad_u32_u24 v44, v43, %[c32], %[vl4]\n\t" \
  "global_load_dwordx4 " r0 ", v44, %[bp]\n\t" \
  "global_load_dwordx4 " r1 ", v44, %[bp] offset:1024\n\t" \
  "global_load_dwordx4 " r2 ", v44, %[bp] offset:2048\n\t" \
  "global_load_dwordx4 " r3 ", v44, %[bp] offset:3072\n\t"

#define PREF0(K) PREF("v[114:117]","v[118:121]","v[122:125]","v[126:129]",K)
#define PREF1(K) PREF("v[130:133]","v[134:137]","v[138:141]","v[142:145]",K)
#define PREF2(K) PREF("v[146:149]","v[150:153]","v[154:157]","v[158:161]",K)
#define PREF3(K) PREF("v[162:165]","v[166:169]","v[170:173]","v[174:177]",K)
#define PREF4(K) PREF("v[178:181]","v[182:185]","v[186:189]","v[190:193]",K)
#define PREF5(K) PREF("v[194:197]","v[198:201]","v[202:205]","v[206:209]",K)
#define PREF6(K) PREF("v[210:213]","v[214:217]","v[218:221]","v[222:225]",K)
#define PREF7(K) PREF("v[226:229]","v[230:233]","v[234:237]","v[238:241]",K)

#define SLOT0 (114,115,116,117,118,119,120,121,122,123,124,125,126,127,128,129)
#define SLOT1 (130,131,132,133,134,135,136,137,138,139,140,141,142,143,144,145)
#define SLOT2 (146,147,148,149,150,151,152,153,154,155,156,157,158,159,160,161)
#define SLOT3 (162,163,164,165,166,167,168,169,170,171,172,173,174,175,176,177)
#define SLOT4 (178,179,180,181,182,183,184,185,186,187,188,189,190,191,192,193)
#define SLOT5 (194,195,196,197,198,199,200,201,202,203,204,205,206,207,208,209)
#define SLOT6 (210,211,212,213,214,215,216,217,218,219,220,221,222,223,224,225)
#define SLOT7 (226,227,228,229,230,231,232,233,234,235,236,237,238,239,240,241)

// Indirection so `M` is rescanned adjacent to the prescan-expanded paren list.
#define DTW_CALL(M, A) M A

#define MV(n) "v_mov_b32 v" #n ", v42\n\t"
#define W28 "s_waitcnt vmcnt(28)\n\t"

__global__ __launch_bounds__(64)
void dtw_wave_kernel(const float* __restrict__ Dm, float* __restrict__ dtwv) {
    const int kb = blockIdx.x;
    const int l  = threadIdx.x;
    const int lc = l < 49 ? l : 49;             // lanes 50-63 mirror lane 49
    const float* __restrict__ Dd = Dm + (size_t)kb * SLAB_;

    const int ti_l = lc >> 2;
    const int Jlo = ti_l >= 2 ? 64 * (ti_l - 2) : 0;
    const int Jhi = min(799, 64 * ti_l + 191);
    const int lo_u = (Jlo == 0) ? (4 * lc) : (Jlo + 4 * lc + 3);
    const int hi_u = min(998, Jhi + 4 * lc + 3);
    const unsigned lofs = (unsigned)(lc << 4);      // 16B per lane (contiguous)

    float res;
    unsigned su_d, st_d;

    asm volatile(
        // ---- init constants & state
        "v_mov_b32 v42, %[vbig]\n\t"
        MV(50) MV(51) MV(52) MV(53) MV(54) MV(55) MV(56) MV(57)
        MV(58) MV(59) MV(60) MV(61) MV(62) MV(63) MV(64) MV(65)
        MV(66) MV(67) MV(68) MV(69) MV(70) MV(71) MV(72) MV(73)
        MV(74) MV(75) MV(76) MV(77) MV(78) MV(79) MV(80) MV(81)
        MV(82) MV(83) MV(84) MV(85) MV(86) MV(87) MV(88) MV(89)
        MV(90) MV(91) MV(92) MV(93) MV(94) MV(95) MV(96) MV(97)
        MV(98) MV(99) MV(100) MV(101) MV(102) MV(103) MV(104) MV(105)
        MV(106) MV(107) MV(108) MV(109) MV(110) MV(111) MV(112) MV(113)
        "v_cndmask_b32 v45, v42, 0, %[msk]\n\t"   // tinE: lane0 -> 0, else BIG
        "v_mov_b32 v46, v42\n\t"                  // tinWE
        "v_mov_b32 v47, v42\n\t"                  // tinO
        "v_mov_b32 v48, v42\n\t"                  // tinWO (read at step 0: BIG)
        "s_mov_b32 %[su], 0\n\t"
        // ---- prefill 8 slots (u = 0..7), 32 loads in flight
        PREF0(0) PREF1(1) PREF2(2) PREF3(3) PREF4(4) PREF5(5) PREF6(6) PREF7(7)
        // ---- main loop: 123 iters x 8 steps = steps 0..983
        "1:\n\t"
        W28 DTW_CALL(STEP_E, SLOT0) HO_E PREF0(8)
        W28 DTW_CALL(STEP_O, SLOT1) HO_O PREF1(9)
        W28 DTW_CALL(STEP_E, SLOT2) HO_E PREF2(10)
        W28 DTW_CALL(STEP_O, SLOT3) HO_O PREF3(11)
        W28 DTW_CALL(STEP_E, SLOT4) HO_E PREF4(12)
        W28 DTW_CALL(STEP_O, SLOT5) HO_O PREF5(13)
        W28 DTW_CALL(STEP_E, SLOT6) HO_E PREF6(14)
        W28 DTW_CALL(STEP_O, SLOT7) HO_O PREF7(15)
        "s_add_u32 %[su], %[su], 8\n\t"
        "s_cmp_lg_u32 %[su], 984\n\t"
        "s_cbranch_scc1 1b\n\t"
        // ---- tail: steps 984..998 (su = 984)
        W28 DTW_CALL(STEP_E, SLOT0) HO_E PREF0(8)            // 984, refill 992
        W28 DTW_CALL(STEP_O, SLOT1) HO_O PREF1(9)            // 985, refill 993
        W28 DTW_CALL(STEP_E, SLOT2) HO_E PREF2(10)           // 986, refill 994
        W28 DTW_CALL(STEP_O, SLOT3) HO_O PREF3(11)           // 987, refill 995
        W28 DTW_CALL(STEP_E, SLOT4) HO_E PREF4(12)           // 988, refill 996
        W28 DTW_CALL(STEP_O, SLOT5) HO_O PREF5(13)           // 989, refill 997
        W28 DTW_CALL(STEP_E, SLOT6) HO_E PREF6(14)           // 990, refill 998
        W28 DTW_CALL(STEP_O, SLOT7) HO_O                     // 991
        "s_waitcnt vmcnt(24)\n\t" DTW_CALL(STEP_E, SLOT0) HO_E   // 992
        "s_waitcnt vmcnt(20)\n\t" DTW_CALL(STEP_O, SLOT1) HO_O   // 993
        "s_waitcnt vmcnt(16)\n\t" DTW_CALL(STEP_E, SLOT2) HO_E   // 994
        "s_waitcnt vmcnt(12)\n\t" DTW_CALL(STEP_O, SLOT3) HO_O   // 995
        "s_waitcnt vmcnt(8)\n\t"  DTW_CALL(STEP_E, SLOT4) HO_E   // 996
        "s_waitcnt vmcnt(4)\n\t"  DTW_CALL(STEP_O, SLOT5) HO_O   // 997
        "s_waitcnt vmcnt(0)\n\t"  DTW_CALL(STEP_E, SLOT6)        // 998: lane 49 sO[15]
        "v_mov_b32 %[res], v97\n\t"
        : [res] "=v"(res), [su] "=&s"(su_d), [st] "=&s"(st_d)
        : [vlo] "v"(lo_u), [vhi] "v"(hi_u), [vl4] "v"(lofs),
          [vbig] "v"(BIGV), [wK] "s"(WARP_V), [c32] "s"(4096u),
          [msk] "s"(1ull), [bp] "s"((const void*)Dd)
        : "memory", "scc",
          "v42","v43","v44","v45","v46","v47","v48","v49",
          "v50","v51","v52","v53","v54","v55","v56","v57","v58","v59",
          "v60","v61","v62","v63","v64","v65","v66","v67","v68","v69",
          "v70","v71","v72","v73","v74","v75","v76","v77","v78","v79",
          "v80","v81","v82","v83","v84","v85","v86","v87","v88","v89",
          "v90","v91","v92","v93","v94","v95","v96","v97","v98","v99",
          "v100","v101","v102","v103","v104","v105","v106","v107","v108","v109",
          "v110","v111","v112","v113","v114","v115","v116","v117","v118","v119",
          "v120","v121","v122","v123","v124","v125","v126","v127","v128","v129",
          "v130","v131","v132","v133","v134","v135","v136","v137","v138","v139",
          "v140","v141","v142","v143","v144","v145","v146","v147","v148","v149",
          "v150","v151","v152","v153","v154","v155","v156","v157","v158","v159",
          "v160","v161","v162","v163","v164","v165","v166","v167","v168","v169",
          "v170","v171","v172","v173","v174","v175","v176","v177","v178","v179",
          "v180","v181","v182","v183","v184","v185","v186","v187","v188","v189",
          "v190","v191","v192","v193","v194","v195","v196","v197","v198","v199",
          "v200","v201","v202","v203","v204","v205","v206","v207","v208","v209",
          "v210","v211","v212","v213","v214","v215","v216","v217","v218","v219",
          "v220","v221","v222","v223","v224","v225","v226","v227","v228","v229",
          "v230","v231","v232","v233","v234","v235","v236","v237","v238","v239",
          "v240","v241"
    );

    if (l == 49) dtwv[kb] = res;
}

// ---------------------------------------------------------------- finalize (scalars)
__global__ void finalize_kernel(const float* __restrict__ dtwv, const int* __restrict__ mel_lens,
                                const int* __restrict__ src_lens, const float* __restrict__ durations,
                                const float* __restrict__ mus, const float* __restrict__ log_vars,
                                const int* __restrict__ step, float* __restrict__ out) {
    const int lane = threadIdx.x;  // 64 threads, one wave

    float v = (lane < KB_) ? dtwv[lane] : 0.f;
    for (int o = 32; o; o >>= 1) v += __shfl_down(v, o);

    float w = (lane < B_) ? 1.f / (K_ * (float)mel_lens[lane]) : 0.f;
    for (int o = 32; o; o >>= 1) w += __shfl_down(w, o);

    float du = 0.f;
    if (lane < B_) {
        float s = 0.f;
        for (int j = 0; j < S_; ++j) s += durations[lane * S_ + j];
        du = fabsf(s - (float)mel_lens[lane]) / (float)src_lens[lane];
    }
    for (int o = 32; o; o >>= 1) du += __shfl_down(du, o);

    float kl = 0.f;
    for (int j = lane; j < B_ * Z_; j += 64) {
        float muv = mus[j], lv = log_vars[j];
        kl += 1.f + lv - muv * muv - expf(lv);
    }
    for (int o = 32; o; o >>= 1) kl += __shfl_down(kl, o);

    if (lane == 0) {
        float mel_iter_loss = v / (float)B_;
        float mel_loss = mel_iter_loss * (w / (float)B_);
        float dur_loss = 2.0f * du / (float)B_;
        float kl_loss = -0.5f * kl;
        int st = step[0];
        float beta = (st < 2000) ? 0.f : ((st >= 8000) ? 1.f : (float)(st - 2000) / 6000.f);
        out[0] = mel_loss + dur_loss + beta * kl_loss;
        out[1] = mel_loss;
        out[2] = dur_loss;
        out[3] = kl_loss;
        out[4] = beta;
    }
}

// ---------------------------------------------------------------- launch
extern "C" void kernel_launch(void* const* d_in, const int* in_sizes, int n_in,
                              void* d_out, int out_size, void* d_ws, size_t ws_size,
                              hipStream_t stream) {
    const float* mel_iters   = (const float*)d_in[0];
    const float* mel_targets = (const float*)d_in[1];
    const int*   mel_lens    = (const int*)d_in[2];
    const int*   src_lens    = (const int*)d_in[3];
    const float* durations   = (const float*)d_in[4];
    const float* mus         = (const float*)d_in[5];
    const float* log_vars    = (const float*)d_in[6];
    const int*   step        = (const int*)d_in[7];
    float* out = (float*)d_out;

    float* ws   = (float*)d_ws;
    float* Dm   = ws;                              // 32 * 1,022,976 floats = 131 MB
    float* dtwv = Dm + (size_t)KB_ * SLAB_;        //        32

    fill_edge<<<KB_, 256, 0, stream>>>(Dm);

    gemm_band<<<dim3(5, 13, KB_), 256, 0, stream>>>(mel_iters, mel_targets, Dm);

    dtw_wave_kernel<<<KB_, 64, 0, stream>>>(Dm, dtwv);

    finalize_kernel<<<1, 64, 0, stream>>>(dtwv, mel_lens, src_lens, durations, mus, log_vars, step, out);
}

// Round 11
// 219.306 us; speedup vs baseline: 1.0288x; 1.0288x over previous
//
#include <hip/hip_runtime.h>
#include <math.h>
#include <stdint.h>

// Problem constants (fixed by setup_inputs)
constexpr int K_ = 4, B_ = 8, T_ = 800, C_ = 80, S_ = 128, Z_ = 32;
constexpr int KB_ = K_ * B_;        // 32
constexpr int TC_ = T_ * C_;        // 64000

#define BIGV   1e8f
#define WARP_V 256.0f

// R23 per-lane-stream layout (g=8 shear, corridor-compact):
//   stream(lc, t) = Q[lo_u(lc) + t][16lc .. 16lc+15]   (64B per row)
// where Q[u][i] = D[i][u-(i>>3)] and lo_u/hi_u are the lane's active window
// (len <= 321 <= 336). Only the corridor is materialized: 50 lanes x 336
// rows x 64B = 1.075 MB/problem, 34.4 MB total (vs 131 MB full slab) ->
// L3-resident, FETCH collapses. dtw reads are value-identical to R18:
// t = med3(u - lo_u, 0, len-1)  <=>  row = med3(u, lo_u, hi_u).
constexpr int STRF_ = 336 * 16;              // floats per lane stream (5376)
constexpr int SLAB_ = 50 * STRF_;            // 268,800 floats per problem

__device__ __forceinline__ float sigmoidf_(float v) {
    return 1.f / (1.f + __expf(-v));
}

// ---------------------------------------------------------------- ghost cells j = -1 -> BIG
// Lanes lc<=11 (Jlo==0) read j=-1 in their s=1 half at t=0: floats 8..15.
__global__ void fill_edge(float* __restrict__ Dm) {
    int kb = blockIdx.x;
    int t = threadIdx.x;
    if (t < 96) {
        int lc = t >> 3;
        int pos = 8 + (t & 7);
        Dm[(size_t)kb * SLAB_ + (size_t)lc * STRF_ + pos] = BIGV;
    }
}

// ---------------------------------------------------------------- banded GEMM -> per-lane streams
// R20 single-stage structure; R23 epilogue: g=8 shear, store into streams.
__global__ __launch_bounds__(256) void gemm_band(const float* __restrict__ mel_iters,
                                                 const float* __restrict__ mel_targets,
                                                 float* __restrict__ Dm) {
    const int kb = blockIdx.z;
    const int b  = kb & 7;
    const int ti = blockIdx.y;
    const int tj = ti + (int)blockIdx.x - 2;
    if ((unsigned)tj > 12u) return;

    const float* __restrict__ Xb = mel_iters + (size_t)kb * TC_;
    const float* __restrict__ Yb = mel_targets + (size_t)b * TC_;

    __shared__ float smem[10880];            // xa[80][68] | ya[80][68]; phase2: Zt[71][65]
    __shared__ float x2s[64], y2s[64];
    float (*xa)[68] = (float(*)[68])smem;
    float (*ya)[68] = (float(*)[68])(smem + 5440);

    const int tid = threadIdx.x;
    const int tx = tid & 15, ty = tid >> 4;
    const int i0 = ti * 64, j0 = tj * 64;

    // ---- single-stage: sigmoid(X) 64x80 and sigmoid(Y) 64x80 into LDS
    {
        const int row = tid & 63, seg = tid >> 6;      // 4 threads per row
        const int gi = min(i0 + row, T_ - 1);
        const int gj = min(j0 + row, T_ - 1);
        const float4* Xr = (const float4*)(Xb + (size_t)gi * C_);
        const float4* Yr = (const float4*)(Yb + (size_t)gj * C_);
        #pragma unroll
        for (int m = 0; m < 5; ++m) {
            const int k4 = seg * 5 + m;
            float4 xv = Xr[k4], yv = Yr[k4];
            const int k = k4 * 4;
            xa[k + 0][row] = sigmoidf_(xv.x); xa[k + 1][row] = sigmoidf_(xv.y);
            xa[k + 2][row] = sigmoidf_(xv.z); xa[k + 3][row] = sigmoidf_(xv.w);
            ya[k + 0][row] = sigmoidf_(yv.x); ya[k + 1][row] = sigmoidf_(yv.y);
            ya[k + 2][row] = sigmoidf_(yv.z); ya[k + 3][row] = sigmoidf_(yv.w);
        }
    }
    __syncthreads();

    // ---- row norms, k ascending
    if (tid < 64) {
        float s = 0.f;
        for (int k = 0; k < C_; ++k) { float v = xa[k][tid]; s += v * v; }
        x2s[tid] = s;
    } else if (tid < 128) {
        float s = 0.f;
        for (int k = 0; k < C_; ++k) { float v = ya[k][tid - 64]; s += v * v; }
        y2s[tid - 64] = s;
    }

    // ---- 80-deep FMA
    float acc[4][4] = {};
    #pragma unroll 16
    for (int k = 0; k < C_; ++k) {
        float4 av = *(const float4*)&xa[k][ty * 4];
        float4 bv = *(const float4*)&ya[k][tx * 4];
        acc[0][0] += av.x * bv.x; acc[0][1] += av.x * bv.y; acc[0][2] += av.x * bv.z; acc[0][3] += av.x * bv.w;
        acc[1][0] += av.y * bv.x; acc[1][1] += av.y * bv.y; acc[1][2] += av.y * bv.z; acc[1][3] += av.y * bv.w;
        acc[2][0] += av.z * bv.x; acc[2][1] += av.z * bv.y; acc[2][2] += av.z * bv.z; acc[2][3] += av.z * bv.w;
        acc[3][0] += av.w * bv.x; acc[3][1] += av.w * bv.y; acc[3][2] += av.w * bv.z; acc[3][3] += av.w * bv.w;
    }
    __syncthreads();

    float xs2[4], ys2[4];
    #pragma unroll
    for (int r = 0; r < 4; ++r) xs2[r] = x2s[ty * 4 + r];
    #pragma unroll
    for (int c = 0; c < 4; ++c) ys2[c] = y2s[tx * 4 + c];

    // sheared LDS tile (g=8): Zt[u_rel][iLoc], u_rel = 4tx + c + (ty>>1)
    float* Zt = smem;                     // [71][65]
    const int sb = ty >> 1;
    #pragma unroll
    for (int r = 0; r < 4; ++r)
        #pragma unroll
        for (int c = 0; c < 4; ++c)
            Zt[(4 * tx + c + sb) * 65 + (4 * ty + r)] = xs2[r] + ys2[c] - 2.f * acc[r][c];
    __syncthreads();

    // stream stores: u_global = j0 + 8ti + w; lane chunk lc = 4ti + (lane>>4);
    // t = u_global - lo_u(lc); store stream[lc][t][lane&15].
    const int w0 = tid >> 6;              // wave id 0..3
    const int lane = tid & 63;
    const int iGlob = i0 + lane;
    const int sbl = lane >> 3;            // (i>>3) - 8ti
    const bool iok = iGlob < T_;
    const int lcS = 4 * ti + (lane >> 4);
    const int JloS = ti >= 2 ? 64 * (ti - 2) : 0;
    const int loS = (JloS == 0) ? (2 * lcS) : (JloS + 2 * lcS + 1);
    const int tb = j0 + 8 * ti - loS;     // t for w = 0
    float* lanePtr = Dm + (size_t)kb * SLAB_ + (size_t)lcS * STRF_ + (lane & 15);
    #pragma unroll
    for (int it = 0; it < 18; ++it) {
        int w = w0 + it * 4;
        if (w > 70) break;
        int jrel = w - sbl;
        int tt = tb + w;
        if (iok && (unsigned)jrel < 64u && (j0 + jrel) < T_ && (unsigned)tt < 336u)
            lanePtr[(size_t)tt * 16] = Zt[w * 65 + lane];
    }
}

// ---------------------------------------------------------------- single-wave hard-min DTW, full inline asm
// R23 = exact R18 DP (best measured, absmax 0) with per-lane-stream addressing:
// t = med3(su - lo_u, 0, len-1); addr = lanebase + 64*t (+ offset:0/16/32/48).
// Register map:
//   v42 = BIG  v43,v44 = temps  v45 = tinE  v46 = tinWE  v47 = tinO  v48 = tinWO
//   sE = v50-65  wE = v66-81  sO = v82-97  wO = v98-113
//   ring: 8 slots x 16 floats = v114-v241, 32 loads in flight, wait vmcnt(28)

#define DCELL2(aS,aA,aB,aC,aD,aW, bS,bA,bB,bC,bD,bW) \
  "v_min3_f32 v" #aS ", v" #aA ", v" #aB ", v" #aC "\n\t" \
  "v_min3_f32 v" #bS ", v" #bA ", v" #bB ", v" #bC "\n\t" \
  "v_add_f32 v" #aS ", v" #aS ", v" #aD "\n\t" \
  "v_add_f32 v" #bS ", v" #bS ", v" #bD "\n\t" \
  "v_add_f32 v" #aW ", %[wK], v" #aS "\n\t" \
  "v_add_f32 v" #bW ", %[wK], v" #bS "\n\t"

#define STEP_E(q0,q1,q2,q3,q4,q5,q6,q7,q8,q9,q10,q11,q12,q13,q14,q15) \
  DCELL2(82, 45, 48, 66, q0, 98,    90, 89, 73, 74, q8, 106) \
  DCELL2(83, 50, 98, 67, q1, 99,    91, 58, 106, 75, q9, 107) \
  DCELL2(84, 51, 99, 68, q2, 100,   92, 59, 107, 76, q10, 108) \
  DCELL2(85, 52, 100, 69, q3, 101,  93, 60, 108, 77, q11, 109) \
  DCELL2(86, 53, 101, 70, q4, 102,  94, 61, 109, 78, q12, 110) \
  DCELL2(87, 54, 102, 71, q5, 103,  95, 62, 110, 79, q13, 111) \
  DCELL2(88, 55, 103, 72, q6, 104,  96, 63, 111, 80, q14, 112) \
  DCELL2(89, 56, 104, 73, q7, 105,  97, 64, 112, 81, q15, 113)

#define STEP_O(q0,q1,q2,q3,q4,q5,q6,q7,q8,q9,q10,q11,q12,q13,q14,q15) \
  DCELL2(50, 47, 46, 98, q0, 66,    58, 57, 105, 106, q8, 74) \
  DCELL2(51, 82, 66, 99, q1, 67,    59, 90, 74, 107, q9, 75) \
  DCELL2(52, 83, 67, 100, q2, 68,   60, 91, 75, 108, q10, 76) \
  DCELL2(53, 84, 68, 101, q3, 69,   61, 92, 76, 109, q11, 77) \
  DCELL2(54, 85, 69, 102, q4, 70,   62, 93, 77, 110, q12, 78) \
  DCELL2(55, 86, 70, 103, q5, 71,   63, 94, 78, 111, q13, 79) \
  DCELL2(56, 87, 71, 104, q6, 72,   64, 95, 79, 112, q14, 80) \
  DCELL2(57, 88, 72, 105, q7, 73,   65, 96, 80, 113, q15, 81)

#define HO_E \
  "s_nop 1\n\t" \
  "v_mov_b32_dpp v43, v97 wave_shr:1 row_mask:0xf bank_mask:0xf bound_ctrl:0\n\t" \
  "v_cndmask_b32 v45, v43, v42, %[msk]\n\t" \
  "v_add_f32 v46, %[wK], v45\n\t"

#define HO_O \
  "s_nop 1\n\t" \
  "v_mov_b32_dpp v43, v65 wave_shr:1 row_mask:0xf bank_mask:0xf bound_ctrl:0\n\t" \
  "v_cndmask_b32 v47, v43, v42, %[msk]\n\t" \
  "v_add_f32 v48, %[wK], v47\n\t"

#define PREF(r0,r1,r2,r3,K) \
  "s_add_u32 %[st], %[su], " #K "\n\t" \
  "v_sub_u32 v43, %[st], %[vlo]\n\t" \
  "v_med3_i32 v43, v43, 0, %[vlen]\n\t" \
  "v_mad_u32_u24 v44, v43, 64, %[vbase]\n\t" \
  "global_load_dwordx4 " r0 ", v44, %[bp]\n\t" \
  "global_load_dwordx4 " r1 ", v44, %[bp] offset:16\n\t" \
  "global_load_dwordx4 " r2 ", v44, %[bp] offset:32\n\t" \
  "global_load_dwordx4 " r3 ", v44, %[bp] offset:48\n\t"

#define PREF0(K) PREF("v[114:117]","v[118:121]","v[122:125]","v[126:129]",K)
#define PREF1(K) PREF("v[130:133]","v[134:137]","v[138:141]","v[142:145]",K)
#define PREF2(K) PREF("v[146:149]","v[150:153]","v[154:157]","v[158:161]",K)
#define PREF3(K) PREF("v[162:165]","v[166:169]","v[170:173]","v[174:177]",K)
#define PREF4(K) PREF("v[178:181]","v[182:185]","v[186:189]","v[190:193]",K)
#define PREF5(K) PREF("v[194:197]","v[198:201]","v[202:205]","v[206:209]",K)
#define PREF6(K) PREF("v[210:213]","v[214:217]","v[218:221]","v[222:225]",K)
#define PREF7(K) PREF("v[226:229]","v[230:233]","v[234:237]","v[238:241]",K)

#define SLOT0 (114,115,116,117,118,119,120,121,122,123,124,125,126,127,128,129)
#define SLOT1 (130,131,132,133,134,135,136,137,138,139,140,141,142,143,144,145)
#define SLOT2 (146,147,148,149,150,151,152,153,154,155,156,157,158,159,160,161)
#define SLOT3 (162,163,164,165,166,167,168,169,170,171,172,173,174,175,176,177)
#define SLOT4 (178,179,180,181,182,183,184,185,186,187,188,189,190,191,192,193)
#define SLOT5 (194,195,196,197,198,199,200,201,202,203,204,205,206,207,208,209)
#define SLOT6 (210,211,212,213,214,215,216,217,218,219,220,221,222,223,224,225)
#define SLOT7 (226,227,228,229,230,231,232,233,234,235,236,237,238,239,240,241)

// Indirection so `M` is rescanned adjacent to the prescan-expanded paren list.
#define DTW_CALL(M, A) M A

#define MV(n) "v_mov_b32 v" #n ", v42\n\t"
#define W28 "s_waitcnt vmcnt(28)\n\t"

__global__ __launch_bounds__(64)
void dtw_wave_kernel(const float* __restrict__ Dm, float* __restrict__ dtwv) {
    const int kb = blockIdx.x;
    const int l  = threadIdx.x;
    const int lc = l < 49 ? l : 49;             // lanes 50-63 mirror lane 49
    const float* __restrict__ Dd = Dm + (size_t)kb * SLAB_;

    const int ti_l = lc >> 2;
    const int Jlo = ti_l >= 2 ? 64 * (ti_l - 2) : 0;
    const int Jhi = min(799, 64 * ti_l + 191);
    const int lo_u = (Jlo == 0) ? (2 * lc) : (Jlo + 2 * lc + 1);
    const int hi_u = Jhi + 2 * lc + 1;
    const int lenm1 = hi_u - lo_u;                  // <= 320
    const unsigned vbase = (unsigned)(lc * (STRF_ * 4));   // stream byte base

    float res;
    unsigned su_d, st_d;

    asm volatile(
        // ---- init constants & state
        "v_mov_b32 v42, %[vbig]\n\t"
        MV(50) MV(51) MV(52) MV(53) MV(54) MV(55) MV(56) MV(57)
        MV(58) MV(59) MV(60) MV(61) MV(62) MV(63) MV(64) MV(65)
        MV(66) MV(67) MV(68) MV(69) MV(70) MV(71) MV(72) MV(73)
        MV(74) MV(75) MV(76) MV(77) MV(78) MV(79) MV(80) MV(81)
        MV(82) MV(83) MV(84) MV(85) MV(86) MV(87) MV(88) MV(89)
        MV(90) MV(91) MV(92) MV(93) MV(94) MV(95) MV(96) MV(97)
        MV(98) MV(99) MV(100) MV(101) MV(102) MV(103) MV(104) MV(105)
        MV(106) MV(107) MV(108) MV(109) MV(110) MV(111) MV(112) MV(113)
        "v_cndmask_b32 v45, v42, 0, %[msk]\n\t"   // tinE: lane0 -> 0, else BIG
        "v_mov_b32 v46, v42\n\t"                  // tinWE
        "v_mov_b32 v47, v42\n\t"                  // tinO
        "v_mov_b32 v48, v42\n\t"                  // tinWO (read at step 0: BIG)
        "s_mov_b32 %[su], 0\n\t"
        // ---- prefill 8 slots (u = 0..7), 32 loads in flight
        PREF0(0) PREF1(1) PREF2(2) PREF3(3) PREF4(4) PREF5(5) PREF6(6) PREF7(7)
        // ---- main loop: 111 iters x 8 steps = steps 0..887
        "1:\n\t"
        W28 DTW_CALL(STEP_E, SLOT0) HO_E PREF0(8)
        W28 DTW_CALL(STEP_O, SLOT1) HO_O PREF1(9)
        W28 DTW_CALL(STEP_E, SLOT2) HO_E PREF2(10)
        W28 DTW_CALL(STEP_O, SLOT3) HO_O PREF3(11)
        W28 DTW_CALL(STEP_E, SLOT4) HO_E PREF4(12)
        W28 DTW_CALL(STEP_O, SLOT5) HO_O PREF5(13)
        W28 DTW_CALL(STEP_E, SLOT6) HO_E PREF6(14)
        W28 DTW_CALL(STEP_O, SLOT7) HO_O PREF7(15)
        "s_add_u32 %[su], %[su], 8\n\t"
        "s_cmp_lg_u32 %[su], 888\n\t"
        "s_cbranch_scc1 1b\n\t"
        // ---- tail: steps 888..898 (su = 888)
        W28 DTW_CALL(STEP_E, SLOT0) HO_E PREF0(8)            // 888, refill 896
        W28 DTW_CALL(STEP_O, SLOT1) HO_O PREF1(9)            // 889, refill 897
        W28 DTW_CALL(STEP_E, SLOT2) HO_E PREF2(10)           // 890, refill 898
        W28 DTW_CALL(STEP_O, SLOT3) HO_O                     // 891
        "s_waitcnt vmcnt(24)\n\t" DTW_CALL(STEP_E, SLOT4) HO_E   // 892
        "s_waitcnt vmcnt(20)\n\t" DTW_CALL(STEP_O, SLOT5) HO_O   // 893
        "s_waitcnt vmcnt(16)\n\t" DTW_CALL(STEP_E, SLOT6) HO_E   // 894
        "s_waitcnt vmcnt(12)\n\t" DTW_CALL(STEP_O, SLOT7) HO_O   // 895
        "s_waitcnt vmcnt(8)\n\t"  DTW_CALL(STEP_E, SLOT0) HO_E   // 896
        "s_waitcnt vmcnt(4)\n\t"  DTW_CALL(STEP_O, SLOT1) HO_O   // 897
        "s_waitcnt vmcnt(0)\n\t"  DTW_CALL(STEP_E, SLOT2)        // 898
        "v_mov_b32 %[res], v97\n\t"
        : [res] "=v"(res), [su] "=&s"(su_d), [st] "=&s"(st_d)
        : [vlo] "v"(lo_u), [vlen] "v"(lenm1), [vbase] "v"(vbase),
          [vbig] "v"(BIGV), [wK] "s"(WARP_V),
          [msk] "s"(1ull), [bp] "s"((const void*)Dd)
        : "memory", "scc",
          "v42","v43","v44","v45","v46","v47","v48","v49",
          "v50","v51","v52","v53","v54","v55","v56","v57","v58","v59",
          "v60","v61","v62","v63","v64","v65","v66","v67","v68","v69",
          "v70","v71","v72","v73","v74","v75","v76","v77","v78","v79",
          "v80","v81","v82","v83","v84","v85","v86","v87","v88","v89",
          "v90","v91","v92","v93","v94","v95","v96","v97","v98","v99",
          "v100","v101","v102","v103","v104","v105","v106","v107","v108","v109",
          "v110","v111","v112","v113","v114","v115","v116","v117","v118","v119",
          "v120","v121","v122","v123","v124","v125","v126","v127","v128","v129",
          "v130","v131","v132","v133","v134","v135","v136","v137","v138","v139",
          "v140","v141","v142","v143","v144","v145","v146","v147","v148","v149",
          "v150","v151","v152","v153","v154","v155","v156","v157","v158","v159",
          "v160","v161","v162","v163","v164","v165","v166","v167","v168","v169",
          "v170","v171","v172","v173","v174","v175","v176","v177","v178","v179",
          "v180","v181","v182","v183","v184","v185","v186","v187","v188","v189",
          "v190","v191","v192","v193","v194","v195","v196","v197","v198","v199",
          "v200","v201","v202","v203","v204","v205","v206","v207","v208","v209",
          "v210","v211","v212","v213","v214","v215","v216","v217","v218","v219",
          "v220","v221","v222","v223","v224","v225","v226","v227","v228","v229",
          "v230","v231","v232","v233","v234","v235","v236","v237","v238","v239",
          "v240","v241"
    );

    if (l == 49) dtwv[kb] = res;
}

// ---------------------------------------------------------------- finalize (scalars)
__global__ void finalize_kernel(const float* __restrict__ dtwv, const int* __restrict__ mel_lens,
                                const int* __restrict__ src_lens, const float* __restrict__ durations,
                                const float* __restrict__ mus, const float* __restrict__ log_vars,
                                const int* __restrict__ step, float* __restrict__ out) {
    const int lane = threadIdx.x;  // 64 threads, one wave

    float v = (lane < KB_) ? dtwv[lane] : 0.f;
    for (int o = 32; o; o >>= 1) v += __shfl_down(v, o);

    float w = (lane < B_) ? 1.f / (K_ * (float)mel_lens[lane]) : 0.f;
    for (int o = 32; o; o >>= 1) w += __shfl_down(w, o);

    float du = 0.f;
    if (lane < B_) {
        float s = 0.f;
        for (int j = 0; j < S_; ++j) s += durations[lane * S_ + j];
        du = fabsf(s - (float)mel_lens[lane]) / (float)src_lens[lane];
    }
    for (int o = 32; o; o >>= 1) du += __shfl_down(du, o);

    float kl = 0.f;
    for (int j = lane; j < B_ * Z_; j += 64) {
        float muv = mus[j], lv = log_vars[j];
        kl += 1.f + lv - muv * muv - expf(lv);
    }
    for (int o = 32; o; o >>= 1) kl += __shfl_down(kl, o);

    if (lane == 0) {
        float mel_iter_loss = v / (float)B_;
        float mel_loss = mel_iter_loss * (w / (float)B_);
        float dur_loss = 2.0f * du / (float)B_;
        float kl_loss = -0.5f * kl;
        int st = step[0];
        float beta = (st < 2000) ? 0.f : ((st >= 8000) ? 1.f : (float)(st - 2000) / 6000.f);
        out[0] = mel_loss + dur_loss + beta * kl_loss;
        out[1] = mel_loss;
        out[2] = dur_loss;
        out[3] = kl_loss;
        out[4] = beta;
    }
}

// ---------------------------------------------------------------- launch
extern "C" void kernel_launch(void* const* d_in, const int* in_sizes, int n_in,
                              void* d_out, int out_size, void* d_ws, size_t ws_size,
                              hipStream_t stream) {
    const float* mel_iters   = (const float*)d_in[0];
    const float* mel_targets = (const float*)d_in[1];
    const int*   mel_lens    = (const int*)d_in[2];
    const int*   src_lens    = (const int*)d_in[3];
    const float* durations   = (const float*)d_in[4];
    const float* mus         = (const float*)d_in[5];
    const float* log_vars    = (const float*)d_in[6];
    const int*   step        = (const int*)d_in[7];
    float* out = (float*)d_out;

    float* ws   = (float*)d_ws;
    float* Dm   = ws;                              // 32 * 268,800 floats = 34.4 MB
    float* dtwv = Dm + (size_t)KB_ * SLAB_;        //        32

    fill_edge<<<KB_, 96, 0, stream>>>(Dm);

    gemm_band<<<dim3(5, 13, KB_), 256, 0, stream>>>(mel_iters, mel_targets, Dm);

    dtw_wave_kernel<<<KB_, 64, 0, stream>>>(Dm, dtwv);

    finalize_kernel<<<1, 64, 0, stream>>>(dtwv, mel_lens, src_lens, durations, mus, log_vars, step, out);
}

// Round 12
// 210.043 us; speedup vs baseline: 1.0742x; 1.0441x over previous
//
#include <hip/hip_runtime.h>
#include <math.h>
#include <stdint.h>

// Problem constants (fixed by setup_inputs)
constexpr int K_ = 4, B_ = 8, T_ = 800, C_ = 80, S_ = 128, Z_ = 32;
constexpr int KB_ = K_ * B_;        // 32
constexpr int TC_ = T_ * C_;        // 64000

#define BIGV   1e8f
#define GHOSTH 65504.0f             // fp16 max: ghost-cell D (real cells ~5-20K)
#define WARP_V 256.0f

// R24: R18 g=8 sheared-stream layout, element type fp16.
// Q[u][i] = D[i][u - (i>>3)] stored as _Float16; row = 800 halves = 1600 B.
// Lane lc reads halves 16lc..16lc+15 (32 B) per step: 2x global_load_dwordx4.
// Cells consume halves via v_fma_mix_f32 (f16 src, f32 accum) -- replaces the
// f32 add one-for-one; DP chain/register dataflow identical to verified R18.
// Fetch model (fits R18/R22/R23): t = 36us + 4.4us/MB * FETCH -> halving the
// compulsory stream (fp32->fp16) should cut dtw ~35us.
constexpr int NU_   = 900;            // u = j + (i>>3) <= 799 + 99 = 898
constexpr int SLAB_ = NU_ * 800;      // 720,000 halves per problem (46 MB total)

__device__ __forceinline__ float sigmoidf_(float v) {
    return 1.f / (1.f + __expf(-v));
}

// ---------------------------------------------------------------- fill j = -1 ghost cells
// Lanes l<=11 read Q[2l][16l+8..15] = D[i][-1] once (their first step).
__global__ void fill_edge(_Float16* __restrict__ Dm) {
    int kb = blockIdx.x;
    int t = threadIdx.x;
    if (t < 184) {
        int i = 8 + t;     // i in [8, 191]
        Dm[(size_t)kb * SLAB_ + (size_t)((i >> 3) - 1) * 800 + i] = (_Float16)GHOSTH;
    }
}

// ---------------------------------------------------------------- banded GEMM -> sheared Q (norms fused)
// R20 single-stage structure; epilogue stores fp16 (R18 g=8 slab layout).
__global__ __launch_bounds__(256) void gemm_band(const float* __restrict__ mel_iters,
                                                 const float* __restrict__ mel_targets,
                                                 _Float16* __restrict__ Dm) {
    const int kb = blockIdx.z;
    const int b  = kb & 7;
    const int ti = blockIdx.y;
    const int tj = ti + (int)blockIdx.x - 2;
    if ((unsigned)tj > 12u) return;

    const float* __restrict__ Xb = mel_iters + (size_t)kb * TC_;
    const float* __restrict__ Yb = mel_targets + (size_t)b * TC_;

    __shared__ float smem[10880];            // xa[80][68] | ya[80][68]; phase2: Zt[71][65]
    __shared__ float x2s[64], y2s[64];
    float (*xa)[68] = (float(*)[68])smem;
    float (*ya)[68] = (float(*)[68])(smem + 5440);

    const int tid = threadIdx.x;
    const int tx = tid & 15, ty = tid >> 4;
    const int i0 = ti * 64, j0 = tj * 64;

    // ---- single-stage: sigmoid(X) 64x80 and sigmoid(Y) 64x80 into LDS
    {
        const int row = tid & 63, seg = tid >> 6;      // 4 threads per row
        const int gi = min(i0 + row, T_ - 1);
        const int gj = min(j0 + row, T_ - 1);
        const float4* Xr = (const float4*)(Xb + (size_t)gi * C_);
        const float4* Yr = (const float4*)(Yb + (size_t)gj * C_);
        #pragma unroll
        for (int m = 0; m < 5; ++m) {
            const int k4 = seg * 5 + m;
            float4 xv = Xr[k4], yv = Yr[k4];
            const int k = k4 * 4;
            xa[k + 0][row] = sigmoidf_(xv.x); xa[k + 1][row] = sigmoidf_(xv.y);
            xa[k + 2][row] = sigmoidf_(xv.z); xa[k + 3][row] = sigmoidf_(xv.w);
            ya[k + 0][row] = sigmoidf_(yv.x); ya[k + 1][row] = sigmoidf_(yv.y);
            ya[k + 2][row] = sigmoidf_(yv.z); ya[k + 3][row] = sigmoidf_(yv.w);
        }
    }
    __syncthreads();

    // ---- row norms, k ascending
    if (tid < 64) {
        float s = 0.f;
        for (int k = 0; k < C_; ++k) { float v = xa[k][tid]; s += v * v; }
        x2s[tid] = s;
    } else if (tid < 128) {
        float s = 0.f;
        for (int k = 0; k < C_; ++k) { float v = ya[k][tid - 64]; s += v * v; }
        y2s[tid - 64] = s;
    }

    // ---- 80-deep FMA
    float acc[4][4] = {};
    #pragma unroll 16
    for (int k = 0; k < C_; ++k) {
        float4 av = *(const float4*)&xa[k][ty * 4];
        float4 bv = *(const float4*)&ya[k][tx * 4];
        acc[0][0] += av.x * bv.x; acc[0][1] += av.x * bv.y; acc[0][2] += av.x * bv.z; acc[0][3] += av.x * bv.w;
        acc[1][0] += av.y * bv.x; acc[1][1] += av.y * bv.y; acc[1][2] += av.y * bv.z; acc[1][3] += av.y * bv.w;
        acc[2][0] += av.z * bv.x; acc[2][1] += av.z * bv.y; acc[2][2] += av.z * bv.z; acc[2][3] += av.z * bv.w;
        acc[3][0] += av.w * bv.x; acc[3][1] += av.w * bv.y; acc[3][2] += av.w * bv.z; acc[3][3] += av.w * bv.w;
    }
    __syncthreads();

    float xs2[4], ys2[4];
    #pragma unroll
    for (int r = 0; r < 4; ++r) xs2[r] = x2s[ty * 4 + r];
    #pragma unroll
    for (int c = 0; c < 4; ++c) ys2[c] = y2s[tx * 4 + c];

    // sheared LDS tile (g=8): Zt[u_rel][iLoc], u_rel = 4tx + c + (ty>>1)
    float* Zt = smem;                     // [71][65]
    const int sb = ty >> 1;
    #pragma unroll
    for (int r = 0; r < 4; ++r)
        #pragma unroll
        for (int c = 0; c < 4; ++c)
            Zt[(4 * tx + c + sb) * 65 + (4 * ty + r)] = xs2[r] + ys2[c] - 2.f * acc[r][c];
    __syncthreads();

    // coalesced u-row stores (fp16): u_global = j0 + 8ti + w
    const int w0 = tid >> 6;              // wave id 0..3
    const int lane = tid & 63;
    const int iGlob = i0 + lane;
    const int sbl = lane >> 3;            // (i>>3) - 8ti
    const bool iok = iGlob < T_;
    const size_t ub = (size_t)(j0 + 8 * ti) * 800 + iGlob;
    #pragma unroll
    for (int it = 0; it < 18; ++it) {
        int w = w0 + it * 4;
        if (w > 70) break;
        int jrel = w - sbl;
        if (iok && (unsigned)jrel < 64u && (j0 + jrel) < T_)
            Dm[(size_t)kb * SLAB_ + ub + (size_t)w * 800] = (_Float16)Zt[w * 65 + lane];
    }
}

// ---------------------------------------------------------------- single-wave hard-min DTW, fp16 stream
// R24 = exact R18 DP dataflow; D consumed as f16 via v_fma_mix_f32.
// Register map:
//   v42 = BIG  v43,v44 = temps  v45 = tinE  v46 = tinWE  v47 = tinO  v48 = tinWO
//   sE = v50-65  wE = v66-81  sO = v82-97  wO = v98-113
//   ring: 8 slots x 8 dwords (16 halves = 1 step) = v114-v177,
//   16 loads in flight, wait vmcnt(14).

#define DCELL2(aS,aA,aB,aC,aQ,aH,aW, bS,bA,bB,bC,bQ,bH,bW) \
  "v_min3_f32 v" #aS ", v" #aA ", v" #aB ", v" #aC "\n\t" \
  "v_min3_f32 v" #bS ", v" #bA ", v" #bB ", v" #bC "\n\t" \
  "v_fma_mix_f32 v" #aS ", v" #aQ ", 1.0, v" #aS " op_sel:[" #aH ",0,0] op_sel_hi:[1,0,0]\n\t" \
  "v_fma_mix_f32 v" #bS ", v" #bQ ", 1.0, v" #bS " op_sel:[" #bH ",0,0] op_sel_hi:[1,0,0]\n\t" \
  "v_add_f32 v" #aW ", %[wK], v" #aS "\n\t" \
  "v_add_f32 v" #bW ", %[wK], v" #bS "\n\t"

// STEP_E: reads sE/wE (+tinE,tinWO), writes sO/wO. Dword Qk holds halves 2k,2k+1.
#define STEP_E(Q0,Q1,Q2,Q3,Q4,Q5,Q6,Q7) \
  DCELL2(82, 45, 48, 66, Q0,0, 98,    90, 89, 73, 74, Q4,0, 106) \
  DCELL2(83, 50, 98, 67, Q0,1, 99,    91, 58, 106, 75, Q4,1, 107) \
  DCELL2(84, 51, 99, 68, Q1,0, 100,   92, 59, 107, 76, Q5,0, 108) \
  DCELL2(85, 52, 100, 69, Q1,1, 101,  93, 60, 108, 77, Q5,1, 109) \
  DCELL2(86, 53, 101, 70, Q2,0, 102,  94, 61, 109, 78, Q6,0, 110) \
  DCELL2(87, 54, 102, 71, Q2,1, 103,  95, 62, 110, 79, Q6,1, 111) \
  DCELL2(88, 55, 103, 72, Q3,0, 104,  96, 63, 111, 80, Q7,0, 112) \
  DCELL2(89, 56, 104, 73, Q3,1, 105,  97, 64, 112, 81, Q7,1, 113)

#define STEP_O(Q0,Q1,Q2,Q3,Q4,Q5,Q6,Q7) \
  DCELL2(50, 47, 46, 98, Q0,0, 66,    58, 57, 105, 106, Q4,0, 74) \
  DCELL2(51, 82, 66, 99, Q0,1, 67,    59, 90, 74, 107, Q4,1, 75) \
  DCELL2(52, 83, 67, 100, Q1,0, 68,   60, 91, 75, 108, Q5,0, 76) \
  DCELL2(53, 84, 68, 101, Q1,1, 69,   61, 92, 76, 109, Q5,1, 77) \
  DCELL2(54, 85, 69, 102, Q2,0, 70,   62, 93, 77, 110, Q6,0, 78) \
  DCELL2(55, 86, 70, 103, Q2,1, 71,   63, 94, 78, 111, Q6,1, 79) \
  DCELL2(56, 87, 71, 104, Q3,0, 72,   64, 95, 79, 112, Q7,0, 80) \
  DCELL2(57, 88, 72, 105, Q3,1, 73,   65, 96, 80, 113, Q7,1, 81)

#define HO_E \
  "s_nop 1\n\t" \
  "v_mov_b32_dpp v43, v97 wave_shr:1 row_mask:0xf bank_mask:0xf bound_ctrl:0\n\t" \
  "v_cndmask_b32 v45, v43, v42, %[msk]\n\t" \
  "v_add_f32 v46, %[wK], v45\n\t"

#define HO_O \
  "s_nop 1\n\t" \
  "v_mov_b32_dpp v43, v65 wave_shr:1 row_mask:0xf bank_mask:0xf bound_ctrl:0\n\t" \
  "v_cndmask_b32 v47, v43, v42, %[msk]\n\t" \
  "v_add_f32 v48, %[wK], v47\n\t"

#define PREF(r0,r1,K) \
  "s_add_u32 %[st], %[su], " #K "\n\t" \
  "v_med3_i32 v43, %[st], %[vlo], %[vhi]\n\t" \
  "v_mad_u32_u24 v44, v43, %[c32], %[vl4]\n\t" \
  "global_load_dwordx4 " r0 ", v44, %[bp]\n\t" \
  "global_load_dwordx4 " r1 ", v44, %[bp] offset:16\n\t"

#define PREF0(K) PREF("v[114:117]","v[118:121]",K)
#define PREF1(K) PREF("v[122:125]","v[126:129]",K)
#define PREF2(K) PREF("v[130:133]","v[134:137]",K)
#define PREF3(K) PREF("v[138:141]","v[142:145]",K)
#define PREF4(K) PREF("v[146:149]","v[150:153]",K)
#define PREF5(K) PREF("v[154:157]","v[158:161]",K)
#define PREF6(K) PREF("v[162:165]","v[166:169]",K)
#define PREF7(K) PREF("v[170:173]","v[174:177]",K)

#define SLOT0 (114,115,116,117,118,119,120,121)
#define SLOT1 (122,123,124,125,126,127,128,129)
#define SLOT2 (130,131,132,133,134,135,136,137)
#define SLOT3 (138,139,140,141,142,143,144,145)
#define SLOT4 (146,147,148,149,150,151,152,153)
#define SLOT5 (154,155,156,157,158,159,160,161)
#define SLOT6 (162,163,164,165,166,167,168,169)
#define SLOT7 (170,171,172,173,174,175,176,177)

// Indirection so `M` is rescanned adjacent to the prescan-expanded paren list.
#define DTW_CALL(M, A) M A

#define MV(n) "v_mov_b32 v" #n ", v42\n\t"
#define W14 "s_waitcnt vmcnt(14)\n\t"

__global__ __launch_bounds__(64)
void dtw_wave_kernel(const _Float16* __restrict__ Dm, float* __restrict__ dtwv) {
    const int kb = blockIdx.x;
    const int l  = threadIdx.x;
    const int lc = l < 49 ? l : 49;             // lanes 50-63 mirror lane 49
    const _Float16* __restrict__ Dd = Dm + (size_t)kb * SLAB_;

    const int ti_l = lc >> 2;
    const int Jlo = ti_l >= 2 ? 64 * (ti_l - 2) : 0;
    const int Jhi = min(799, 64 * ti_l + 191);
    const int lo_u = (Jlo == 0) ? (2 * lc) : (Jlo + 2 * lc + 1);
    const int hi_u = Jhi + 2 * lc + 1;
    const unsigned lofs = (unsigned)(lc << 5);      // 32 B per lane within row

    float res;
    unsigned su_d, st_d;

    asm volatile(
        // ---- init constants & state
        "v_mov_b32 v42, %[vbig]\n\t"
        MV(50) MV(51) MV(52) MV(53) MV(54) MV(55) MV(56) MV(57)
        MV(58) MV(59) MV(60) MV(61) MV(62) MV(63) MV(64) MV(65)
        MV(66) MV(67) MV(68) MV(69) MV(70) MV(71) MV(72) MV(73)
        MV(74) MV(75) MV(76) MV(77) MV(78) MV(79) MV(80) MV(81)
        MV(82) MV(83) MV(84) MV(85) MV(86) MV(87) MV(88) MV(89)
        MV(90) MV(91) MV(92) MV(93) MV(94) MV(95) MV(96) MV(97)
        MV(98) MV(99) MV(100) MV(101) MV(102) MV(103) MV(104) MV(105)
        MV(106) MV(107) MV(108) MV(109) MV(110) MV(111) MV(112) MV(113)
        "v_cndmask_b32 v45, v42, 0, %[msk]\n\t"   // tinE: lane0 -> 0, else BIG
        "v_mov_b32 v46, v42\n\t"                  // tinWE
        "v_mov_b32 v47, v42\n\t"                  // tinO
        "v_mov_b32 v48, v42\n\t"                  // tinWO (read at step 0: BIG)
        "s_mov_b32 %[su], 0\n\t"
        // ---- prefill 8 slots (u = 0..7), 16 loads in flight
        PREF0(0) PREF1(1) PREF2(2) PREF3(3) PREF4(4) PREF5(5) PREF6(6) PREF7(7)
        // ---- main loop: 111 iters x 8 steps = steps 0..887
        "1:\n\t"
        W14 DTW_CALL(STEP_E, SLOT0) HO_E PREF0(8)
        W14 DTW_CALL(STEP_O, SLOT1) HO_O PREF1(9)
        W14 DTW_CALL(STEP_E, SLOT2) HO_E PREF2(10)
        W14 DTW_CALL(STEP_O, SLOT3) HO_O PREF3(11)
        W14 DTW_CALL(STEP_E, SLOT4) HO_E PREF4(12)
        W14 DTW_CALL(STEP_O, SLOT5) HO_O PREF5(13)
        W14 DTW_CALL(STEP_E, SLOT6) HO_E PREF6(14)
        W14 DTW_CALL(STEP_O, SLOT7) HO_O PREF7(15)
        "s_add_u32 %[su], %[su], 8\n\t"
        "s_cmp_lg_u32 %[su], 888\n\t"
        "s_cbranch_scc1 1b\n\t"
        // ---- tail: steps 888..898 (su = 888)
        W14 DTW_CALL(STEP_E, SLOT0) HO_E PREF0(8)            // 888, refill 896
        W14 DTW_CALL(STEP_O, SLOT1) HO_O PREF1(9)            // 889, refill 897
        W14 DTW_CALL(STEP_E, SLOT2) HO_E PREF2(10)           // 890, refill 898
        W14 DTW_CALL(STEP_O, SLOT3) HO_O                     // 891
        "s_waitcnt vmcnt(12)\n\t" DTW_CALL(STEP_E, SLOT4) HO_E   // 892
        "s_waitcnt vmcnt(10)\n\t" DTW_CALL(STEP_O, SLOT5) HO_O   // 893
        "s_waitcnt vmcnt(8)\n\t"  DTW_CALL(STEP_E, SLOT6) HO_E   // 894
        "s_waitcnt vmcnt(6)\n\t"  DTW_CALL(STEP_O, SLOT7) HO_O   // 895
        "s_waitcnt vmcnt(4)\n\t"  DTW_CALL(STEP_E, SLOT0) HO_E   // 896
        "s_waitcnt vmcnt(2)\n\t"  DTW_CALL(STEP_O, SLOT1) HO_O   // 897
        "s_waitcnt vmcnt(0)\n\t"  DTW_CALL(STEP_E, SLOT2)        // 898
        "v_mov_b32 %[res], v97\n\t"
        : [res] "=v"(res), [su] "=&s"(su_d), [st] "=&s"(st_d)
        : [vlo] "v"(lo_u), [vhi] "v"(hi_u), [vl4] "v"(lofs),
          [vbig] "v"(BIGV), [wK] "s"(WARP_V), [c32] "s"(1600u),
          [msk] "s"(1ull), [bp] "s"((const void*)Dd)
        : "memory", "scc",
          "v42","v43","v44","v45","v46","v47","v48","v49",
          "v50","v51","v52","v53","v54","v55","v56","v57","v58","v59",
          "v60","v61","v62","v63","v64","v65","v66","v67","v68","v69",
          "v70","v71","v72","v73","v74","v75","v76","v77","v78","v79",
          "v80","v81","v82","v83","v84","v85","v86","v87","v88","v89",
          "v90","v91","v92","v93","v94","v95","v96","v97","v98","v99",
          "v100","v101","v102","v103","v104","v105","v106","v107","v108","v109",
          "v110","v111","v112","v113","v114","v115","v116","v117","v118","v119",
          "v120","v121","v122","v123","v124","v125","v126","v127","v128","v129",
          "v130","v131","v132","v133","v134","v135","v136","v137","v138","v139",
          "v140","v141","v142","v143","v144","v145","v146","v147","v148","v149",
          "v150","v151","v152","v153","v154","v155","v156","v157","v158","v159",
          "v160","v161","v162","v163","v164","v165","v166","v167","v168","v169",
          "v170","v171","v172","v173","v174","v175","v176","v177"
    );

    if (l == 49) dtwv[kb] = res;
}

// ---------------------------------------------------------------- finalize (scalars)
__global__ void finalize_kernel(const float* __restrict__ dtwv, const int* __restrict__ mel_lens,
                                const int* __restrict__ src_lens, const float* __restrict__ durations,
                                const float* __restrict__ mus, const float* __restrict__ log_vars,
                                const int* __restrict__ step, float* __restrict__ out) {
    const int lane = threadIdx.x;  // 64 threads, one wave

    float v = (lane < KB_) ? dtwv[lane] : 0.f;
    for (int o = 32; o; o >>= 1) v += __shfl_down(v, o);

    float w = (lane < B_) ? 1.f / (K_ * (float)mel_lens[lane]) : 0.f;
    for (int o = 32; o; o >>= 1) w += __shfl_down(w, o);

    float du = 0.f;
    if (lane < B_) {
        float s = 0.f;
        for (int j = 0; j < S_; ++j) s += durations[lane * S_ + j];
        du = fabsf(s - (float)mel_lens[lane]) / (float)src_lens[lane];
    }
    for (int o = 32; o; o >>= 1) du += __shfl_down(du, o);

    float kl = 0.f;
    for (int j = lane; j < B_ * Z_; j += 64) {
        float muv = mus[j], lv = log_vars[j];
        kl += 1.f + lv - muv * muv - expf(lv);
    }
    for (int o = 32; o; o >>= 1) kl += __shfl_down(kl, o);

    if (lane == 0) {
        float mel_iter_loss = v / (float)B_;
        float mel_loss = mel_iter_loss * (w / (float)B_);
        float dur_loss = 2.0f * du / (float)B_;
        float kl_loss = -0.5f * kl;
        int st = step[0];
        float beta = (st < 2000) ? 0.f : ((st >= 8000) ? 1.f : (float)(st - 2000) / 6000.f);
        out[0] = mel_loss + dur_loss + beta * kl_loss;
        out[1] = mel_loss;
        out[2] = dur_loss;
        out[3] = kl_loss;
        out[4] = beta;
    }
}

// ---------------------------------------------------------------- launch
extern "C" void kernel_launch(void* const* d_in, const int* in_sizes, int n_in,
                              void* d_out, int out_size, void* d_ws, size_t ws_size,
                              hipStream_t stream) {
    const float* mel_iters   = (const float*)d_in[0];
    const float* mel_targets = (const float*)d_in[1];
    const int*   mel_lens    = (const int*)d_in[2];
    const int*   src_lens    = (const int*)d_in[3];
    const float* durations   = (const float*)d_in[4];
    const float* mus         = (const float*)d_in[5];
    const float* log_vars    = (const float*)d_in[6];
    const int*   step        = (const int*)d_in[7];
    float* out = (float*)d_out;

    _Float16* Dm = (_Float16*)d_ws;                               // 32 * 720,000 halves = 46 MB
    float* dtwv  = (float*)((char*)d_ws + (size_t)KB_ * SLAB_ * sizeof(_Float16));

    fill_edge<<<KB_, 192, 0, stream>>>(Dm);

    gemm_band<<<dim3(5, 13, KB_), 256, 0, stream>>>(mel_iters, mel_targets, Dm);

    dtw_wave_kernel<<<KB_, 64, 0, stream>>>(Dm, dtwv);

    finalize_kernel<<<1, 64, 0, stream>>>(dtwv, mel_lens, src_lens, durations, mus, log_vars, step, out);
}